// Round 3
// baseline (274.941 us; speedup 1.0000x reference)
//
#include <hip/hip_runtime.h>
#include <stdint.h>

#define MDIM 2048
#define KDIM 4096
#define NDIM 8192
#define NG   32            // K / GROUP_SIZE
#define QROW 2048          // int32 per qweight row (each int32 holds one byte = 2 nibbles)

typedef __attribute__((ext_vector_type(4))) float    f32x4;
typedef __attribute__((ext_vector_type(2))) _Float16 f16x2;
typedef __attribute__((ext_vector_type(8))) _Float16 f16x8;
typedef __attribute__((ext_vector_type(4))) int      i32x4;

#define CVT2(a, b) __builtin_bit_cast(f16x2, __builtin_amdgcn_cvt_pkrtz((a), (b)))

// 128x128 output tile, BK=32, 4 waves (2x2), each wave 64x64 via 4x4 frags of 16x16x32 f16 MFMA.
__global__ __launch_bounds__(256, 2) void qlin_kernel(
    const float* __restrict__ A,       // [M,K] f32 (fp16-valued)
    const int*   __restrict__ qw,      // [N, K/2] int32, one byte each; lo nibble = even k
    const float* __restrict__ scales,  // [N, 32] f32
    const float* __restrict__ zeros,   // [N, 32] f32
    const float* __restrict__ bias,    // [N] f32
    float* __restrict__ out)           // [M,N] f32
{
  __shared__ _Float16 As[128 * 32];
  __shared__ _Float16 Bs[128 * 32];

  const int tid  = threadIdx.x;
  const int wave = tid >> 6;
  const int lane = tid & 63;
  const int n0 = blockIdx.x << 7;
  const int m0 = blockIdx.y << 7;
  const int wm = (wave >> 1) << 6;
  const int wn = (wave & 1) << 6;

  f32x4 acc[4][4] = {};

  // staging assignment: row r4 (and r4+64), 8-element k-chunk c4
  const int r4 = tid >> 2;      // 0..63
  const int c4 = tid & 3;       // 0..3

  const float* aP0 = A + (size_t)(m0 + r4) * KDIM + c4 * 8;
  const float* aP1 = aP0 + (size_t)64 * KDIM;
  const int*   qP0 = qw + (size_t)(n0 + r4) * QROW + c4 * 4;
  const int*   qP1 = qP0 + (size_t)64 * QROW;
  const int srow0 = n0 + r4;
  const int srow1 = srow0 + 64;

  const int aDst0 = r4 * 32 + c4 * 8;        // linear [row][32] LDS layout
  const int aDst1 = aDst0 + 64 * 32;

  // fragment addressing: row = base + (lane&15), k = (lane>>4)*8
  const int fr = lane & 15;
  const int k0 = (lane >> 4) * 8;

  for (int kt = 0; kt < KDIM / 32; ++kt) {
    // ---- stage A: f32 -> f16, reg-staged ----
    {
      f32x4 v0, v1, v2, v3;
      __builtin_memcpy(&v0, aP0 + kt * 32,     16);
      __builtin_memcpy(&v1, aP0 + kt * 32 + 4, 16);
      __builtin_memcpy(&v2, aP1 + kt * 32,     16);
      __builtin_memcpy(&v3, aP1 + kt * 32 + 4, 16);
      f16x2 h0 = CVT2(v0.x, v0.y);
      f16x2 h1 = CVT2(v0.z, v0.w);
      f16x2 h2 = CVT2(v1.x, v1.y);
      f16x2 h3 = CVT2(v1.z, v1.w);
      _Float16 t0[8] = {h0[0], h0[1], h1[0], h1[1], h2[0], h2[1], h3[0], h3[1]};
      __builtin_memcpy(&As[aDst0], t0, 16);
      f16x2 h4 = CVT2(v2.x, v2.y);
      f16x2 h5 = CVT2(v2.z, v2.w);
      f16x2 h6 = CVT2(v3.x, v3.y);
      f16x2 h7 = CVT2(v3.z, v3.w);
      _Float16 t1[8] = {h4[0], h4[1], h5[0], h5[1], h6[0], h6[1], h7[0], h7[1]};
      __builtin_memcpy(&As[aDst1], t1, 16);
    }

    // ---- stage B: fused dequant to fp16 ----
    // 0x6400|q = fp16(1024+q) exactly; w = ((1024+q)-1024)*s + (-z*s) via pk ops.
    const int g = kt >> 2;   // k-group: kt*32/128
    {
      i32x4 q0, q1;
      __builtin_memcpy(&q0, qP0 + kt * 16, 16);
      __builtin_memcpy(&q1, qP1 + kt * 16, 16);

      auto dequant8 = [&](i32x4 q, int srow, int dstIdx) {
        const float sf = scales[srow * NG + g];
        const float zf = zeros[srow * NG + g];
        const _Float16 sh = (_Float16)sf;
        const _Float16 bh = (_Float16)(-zf * sf);
        const f16x2 s2 = {sh, sh};
        const f16x2 b2 = {bh, bh};
        const f16x2 k2 = {(_Float16)1024.0f, (_Float16)1024.0f};
        _Float16 t[8];
#pragma unroll
        for (int e = 0; e < 4; ++e) {
          unsigned Bb = (unsigned)q[e] & 0xFFu;
          unsigned bits = ((Bb | (Bb << 12)) & 0x000F000Fu) | 0x64006400u;
          f16x2 qv = __builtin_bit_cast(f16x2, bits);
          f16x2 w2 = (qv - k2) * s2 + b2;
          t[2 * e]     = w2[0];   // low nibble = earlier k
          t[2 * e + 1] = w2[1];
        }
        __builtin_memcpy(&Bs[dstIdx], t, 16);
      };
      dequant8(q0, srow0, aDst0);
      dequant8(q1, srow1, aDst1);
    }

    __syncthreads();

    f16x8 af[4], bfr[4];
#pragma unroll
    for (int i = 0; i < 4; ++i)
      __builtin_memcpy(&af[i], &As[(wm + i * 16 + fr) * 32 + k0], 16);
#pragma unroll
    for (int j = 0; j < 4; ++j)
      __builtin_memcpy(&bfr[j], &Bs[(wn + j * 16 + fr) * 32 + k0], 16);

#pragma unroll
    for (int i = 0; i < 4; ++i)
#pragma unroll
      for (int j = 0; j < 4; ++j)
        acc[i][j] = __builtin_amdgcn_mfma_f32_16x16x32_f16(af[i], bfr[j], acc[i][j], 0, 0, 0);

    __syncthreads();
  }

  // epilogue: C/D layout col = lane&15, row = (lane>>4)*4 + reg
  const int cr = (lane >> 4) << 2;
  const int cc = lane & 15;
#pragma unroll
  for (int j = 0; j < 4; ++j) {
    const int n = n0 + wn + j * 16 + cc;
    const float bv = bias[n];
#pragma unroll
    for (int i = 0; i < 4; ++i) {
      const int mrow = m0 + wm + i * 16 + cr;
#pragma unroll
      for (int r = 0; r < 4; ++r)
        out[(size_t)(mrow + r) * NDIM + n] = acc[i][j][r] + bv;
    }
  }
}

extern "C" void kernel_launch(void* const* d_in, const int* in_sizes, int n_in,
                              void* d_out, int out_size, void* d_ws, size_t ws_size,
                              hipStream_t stream) {
  const float* A      = (const float*)d_in[0];
  const int*   qwp    = (const int*)d_in[1];
  const float* scales = (const float*)d_in[2];
  const float* zerosp = (const float*)d_in[3];
  const float* biasp  = (const float*)d_in[4];
  float*       outp   = (float*)d_out;

  dim3 grid(NDIM / 128, MDIM / 128);  // 64 x 16
  qlin_kernel<<<grid, 256, 0, stream>>>(A, qwp, scales, zerosp, biasp, outp);
}